// Round 1
// baseline (21611.169 us; speedup 1.0000x reference)
//
#include <hip/hip_runtime.h>
#include <math.h>

#define BATCH 512
#define TLEN  64
#define HD    512
#define H2    1024
#define H3    1536
#define HQ    51
#define CHUNK 4096

struct Task { int b, sl, sr, jl; };

__device__ __forceinline__ float sigf(float x) { return 1.0f / (1.0f + expf(-x)); }

// ---------------- prep: h copy, weight transposes, pos/rti/counter init ----------------
__global__ void k_prep(const float* __restrict__ inp, const float* __restrict__ W1, const float* __restrict__ W2,
                       float* __restrict__ h, float* __restrict__ W1T, float* __restrict__ W2T,
                       int* __restrict__ pos, int* __restrict__ rti0, int* __restrict__ rti1,
                       int* __restrict__ counters)
{
    long tid = (long)blockIdx.x * blockDim.x + threadIdx.x;
    long nth = (long)gridDim.x * blockDim.x;
    const float4* in4 = (const float4*)inp;
    float4* h4 = (float4*)h;
    for (long i = tid; i < (long)BATCH * TLEN * HD / 4; i += nth) h4[i] = in4[i];
    for (long i = tid; i < (long)H2 * H3; i += nth) {
        long k = i / H3, r = i - k * H3;
        W1T[i] = W1[r * H2 + k];
    }
    for (long i = tid; i < (long)H2 * HD; i += nth) {
        long k = i / HD, r = i - k * HD;
        W2T[i] = W2[r * H2 + k];
    }
    for (long i = tid; i < BATCH * TLEN; i += nth) pos[i] = (int)(i % TLEN);
    for (long i = tid; i < BATCH * 2; i += nth) { rti0[i] = -1; rti1[i] = -1; }
    if (tid < 8) counters[tid] = 0;
}

// ---------------- initial task list: all valid pairs (j < len-1) ----------------
__global__ void k_init_tasks(const int* __restrict__ length, Task* __restrict__ tasks, int* __restrict__ cnt)
{
    int b = blockIdx.x, j = threadIdx.x;
    int len = length[b];
    if (j < len - 1) {
        int idx = atomicAdd(cnt, 1);
        Task t; t.b = b; t.sl = j; t.sr = j + 1; t.jl = j;
        tasks[idx] = t;
    }
}

// ---------------- G1: V = [hl,hr] @ W1^T + b1 ; r-part fused into X2 = [hl*rs, hr*rs] ----------------
// tile: 64 tasks x 64 cols of 1536, K=1024, BK=32, 256 threads, 4x4 micro
__launch_bounds__(256, 2)
__global__ void k_g1(const Task* __restrict__ tasks, const int* __restrict__ cnt, int task_off,
                     const float* __restrict__ h, const float* __restrict__ W1T, const float* __restrict__ b1,
                     float* __restrict__ Vif, float* __restrict__ X2,
                     int* z0, int* z1)
{
    if (z0 && blockIdx.x == 0 && blockIdx.y == 0 && threadIdx.x == 0) { *z0 = 0; if (z1) *z1 = 0; }
    __shared__ float Xs[64][33];
    __shared__ float Ws[32][64];
    __shared__ int tb[64], tsl[64], tsr[64], tok[64];
    int count = *cnt;
    int m_base = task_off + blockIdx.x * 64;
    if (m_base >= count) return;
    int tid = threadIdx.x;
    if (tid < 64) {
        int mg = m_base + tid;
        if (mg < count) { Task t = tasks[mg]; tb[tid] = t.b; tsl[tid] = t.sl; tsr[tid] = t.sr; tok[tid] = 1; }
        else            { tb[tid] = 0; tsl[tid] = 0; tsr[tid] = 0; tok[tid] = 0; }
    }
    __syncthreads();
    const int n0 = blockIdx.y * 64;
    const int ty = tid >> 4, tx = tid & 15;
    const int mrow = tid >> 2, mk = (tid & 3) * 8;
    const int wrow = tid >> 3, wn = (tid & 7) * 8;
    float acc[4][4] = {};
    for (int kt = 0; kt < 32; ++kt) {
        int k0 = kt * 32;
        {
            int slot = (k0 < HD) ? tsl[mrow] : tsr[mrow];
            int kg = (k0 < HD) ? (k0 + mk) : (k0 + mk - HD);
            const float* src = &h[((long)tb[mrow] * TLEN + slot) * HD + kg];
            float4 v0 = *(const float4*)src;
            float4 v1 = *(const float4*)(src + 4);
            float* xd = &Xs[mrow][mk];
            xd[0] = v0.x; xd[1] = v0.y; xd[2] = v0.z; xd[3] = v0.w;
            xd[4] = v1.x; xd[5] = v1.y; xd[6] = v1.z; xd[7] = v1.w;
        }
        {
            const float* src = &W1T[(long)(k0 + wrow) * H3 + n0 + wn];
            float4 v0 = *(const float4*)src;
            float4 v1 = *(const float4*)(src + 4);
            float* wd = &Ws[wrow][wn];
            *(float4*)wd = v0;
            *(float4*)(wd + 4) = v1;
        }
        __syncthreads();
        #pragma unroll
        for (int kk = 0; kk < 32; ++kk) {
            float4 wv = *(const float4*)&Ws[kk][tx * 4];
            float a0 = Xs[ty * 4 + 0][kk], a1 = Xs[ty * 4 + 1][kk];
            float a2 = Xs[ty * 4 + 2][kk], a3 = Xs[ty * 4 + 3][kk];
            acc[0][0] += a0 * wv.x; acc[0][1] += a0 * wv.y; acc[0][2] += a0 * wv.z; acc[0][3] += a0 * wv.w;
            acc[1][0] += a1 * wv.x; acc[1][1] += a1 * wv.y; acc[1][2] += a1 * wv.z; acc[1][3] += a1 * wv.w;
            acc[2][0] += a2 * wv.x; acc[2][1] += a2 * wv.y; acc[2][2] += a2 * wv.z; acc[2][3] += a2 * wv.w;
            acc[3][0] += a3 * wv.x; acc[3][1] += a3 * wv.y; acc[3][2] += a3 * wv.z; acc[3][3] += a3 * wv.w;
        }
        __syncthreads();
    }
    const int row0 = blockIdx.x * 64;
    #pragma unroll
    for (int mi = 0; mi < 4; ++mi) {
        int ml = ty * 4 + mi;
        if (!tok[ml]) continue;
        int row = row0 + ml;
        int c = n0 + tx * 4;
        float4 v;
        v.x = acc[mi][0] + b1[c + 0];
        v.y = acc[mi][1] + b1[c + 1];
        v.z = acc[mi][2] + b1[c + 2];
        v.w = acc[mi][3] + b1[c + 3];
        if (n0 < H2) {
            *(float4*)&Vif[(long)row * H2 + c] = v;
        } else {
            int c2 = c - H2;
            float4 rs;
            rs.x = sigf(v.x); rs.y = sigf(v.y); rs.z = sigf(v.z); rs.w = sigf(v.w);
            const float* hl = &h[((long)tb[ml] * TLEN + tsl[ml]) * HD + c2];
            const float* hr = &h[((long)tb[ml] * TLEN + tsr[ml]) * HD + c2];
            float4 l = *(const float4*)hl, r = *(const float4*)hr;
            float4 xl, xr;
            xl.x = l.x * rs.x; xl.y = l.y * rs.y; xl.z = l.z * rs.z; xl.w = l.w * rs.w;
            xr.x = r.x * rs.x; xr.y = r.y * rs.y; xr.z = r.z * rs.z; xr.w = r.w * rs.w;
            *(float4*)&X2[(long)row * H2 + c2] = xl;
            *(float4*)&X2[(long)row * H2 + HD + c2] = xr;
        }
    }
}

// ---------------- G2: h_hat = X2 @ W2^T + b2 ; fused new_h epilogue ----------------
// mode 0: write newh buffer (refresh); mode 1: write h[b][sl] (merge)
__launch_bounds__(256, 2)
__global__ void k_g2(const Task* __restrict__ tasks, const int* __restrict__ cnt, int task_off,
                     float* __restrict__ h, const float* __restrict__ X2, const float* __restrict__ Vif,
                     const float* __restrict__ W2T, const float* __restrict__ b2,
                     float* __restrict__ newh, int mode)
{
    __shared__ float Xs[64][33];
    __shared__ float Ws[32][64];
    __shared__ int tb[64], tsl[64], tsr[64], tok[64];
    int count = *cnt;
    int m_base = task_off + blockIdx.x * 64;
    if (m_base >= count) return;
    int tid = threadIdx.x;
    if (tid < 64) {
        int mg = m_base + tid;
        if (mg < count) { Task t = tasks[mg]; tb[tid] = t.b; tsl[tid] = t.sl; tsr[tid] = t.sr; tok[tid] = 1; }
        else            { tb[tid] = 0; tsl[tid] = 0; tsr[tid] = 0; tok[tid] = 0; }
    }
    __syncthreads();
    const int n0 = blockIdx.y * 64;
    const int ty = tid >> 4, tx = tid & 15;
    const int mrow = tid >> 2, mk = (tid & 3) * 8;
    const int wrow = tid >> 3, wn = (tid & 7) * 8;
    const int row0 = blockIdx.x * 64;
    float acc[4][4] = {};
    for (int kt = 0; kt < 32; ++kt) {
        int k0 = kt * 32;
        {
            const float* src = &X2[(long)(row0 + mrow) * H2 + k0 + mk];
            float4 v0 = *(const float4*)src;
            float4 v1 = *(const float4*)(src + 4);
            float* xd = &Xs[mrow][mk];
            xd[0] = v0.x; xd[1] = v0.y; xd[2] = v0.z; xd[3] = v0.w;
            xd[4] = v1.x; xd[5] = v1.y; xd[6] = v1.z; xd[7] = v1.w;
        }
        {
            const float* src = &W2T[(long)(k0 + wrow) * HD + n0 + wn];
            float4 v0 = *(const float4*)src;
            float4 v1 = *(const float4*)(src + 4);
            float* wd = &Ws[wrow][wn];
            *(float4*)wd = v0;
            *(float4*)(wd + 4) = v1;
        }
        __syncthreads();
        #pragma unroll
        for (int kk = 0; kk < 32; ++kk) {
            float4 wv = *(const float4*)&Ws[kk][tx * 4];
            float a0 = Xs[ty * 4 + 0][kk], a1 = Xs[ty * 4 + 1][kk];
            float a2 = Xs[ty * 4 + 2][kk], a3 = Xs[ty * 4 + 3][kk];
            acc[0][0] += a0 * wv.x; acc[0][1] += a0 * wv.y; acc[0][2] += a0 * wv.z; acc[0][3] += a0 * wv.w;
            acc[1][0] += a1 * wv.x; acc[1][1] += a1 * wv.y; acc[1][2] += a1 * wv.z; acc[1][3] += a1 * wv.w;
            acc[2][0] += a2 * wv.x; acc[2][1] += a2 * wv.y; acc[2][2] += a2 * wv.z; acc[2][3] += a2 * wv.w;
            acc[3][0] += a3 * wv.x; acc[3][1] += a3 * wv.y; acc[3][2] += a3 * wv.z; acc[3][3] += a3 * wv.w;
        }
        __syncthreads();
    }
    #pragma unroll
    for (int mi = 0; mi < 4; ++mi) {
        int ml = ty * 4 + mi;
        if (!tok[ml]) continue;
        int row = row0 + ml;
        int c = n0 + tx * 4;
        float4 hh;
        hh.x = acc[mi][0] + b2[c + 0];
        hh.y = acc[mi][1] + b2[c + 1];
        hh.z = acc[mi][2] + b2[c + 2];
        hh.w = acc[mi][3] + b2[c + 3];
        float4 vi = *(const float4*)&Vif[(long)row * H2 + c];
        float4 vf = *(const float4*)&Vif[(long)row * H2 + HD + c];
        float* hlp = &h[((long)tb[ml] * TLEN + tsl[ml]) * HD + c];
        const float* hrp = &h[((long)tb[ml] * TLEN + tsr[ml]) * HD + c];
        float4 l = *(const float4*)hlp, r = *(const float4*)hrp;
        float4 nh;
        nh.x = (l.x + r.x) * sigf(vf.x) + tanhf(hh.x) * sigf(vi.x);
        nh.y = (l.y + r.y) * sigf(vf.y) + tanhf(hh.y) * sigf(vi.y);
        nh.z = (l.z + r.z) * sigf(vf.z) + tanhf(hh.z) * sigf(vi.z);
        nh.w = (l.w + r.w) * sigf(vf.w) + tanhf(hh.w) * sigf(vi.w);
        if (mode == 0) *(float4*)&newh[(long)row * HD + c] = nh;
        else           *(float4*)hlp = nh;
    }
}

// ---------------- G3 (init only): comp score per task from newh buffer ----------------
__launch_bounds__(64)
__global__ void k_g3(const Task* __restrict__ tasks, const int* __restrict__ cnt, int task_off,
                     const float* __restrict__ newh_buf,
                     const float* __restrict__ Wq1, const float* __restrict__ bq1,
                     const float* __restrict__ Wq2, const float* __restrict__ bq2,
                     float* __restrict__ comp)
{
    int tgl = task_off + blockIdx.x;
    if (tgl >= *cnt) return;
    int row = blockIdx.x;
    int tid = threadIdx.x;
    __shared__ float nh[HD];
    __shared__ double part[64];
    for (int c = tid; c < HD; c += 64) nh[c] = newh_buf[(long)row * HD + c];
    __syncthreads();
    double p = 0.0;
    if (tid < HQ) {
        double a = (double)bq1[tid];
        const float* wr = &Wq1[(long)tid * HD];
        for (int k = 0; k < HD; ++k) a += (double)wr[k] * (double)nh[k];
        p = tanh(a) * (double)Wq2[tid];
    }
    part[tid] = p;
    __syncthreads();
    if (tid == 0) {
        double s = 0.0;
        for (int r = 0; r < HQ; ++r) s += part[r];
        s += (double)bq2[0];
        Task t = tasks[tgl];
        comp[t.b * TLEN + t.jl] = (float)s;
    }
}

// ---------------- select: refresh comp (<=2), argmax, write mask, apply merge plan ----------------
__launch_bounds__(64)
__global__ void k_select(int iter, long off_i, const int* __restrict__ length,
                         float* __restrict__ comp, int* __restrict__ pos,
                         const int* __restrict__ rti_cur, int* __restrict__ rti_next,
                         const Task* __restrict__ rtasks_cur, Task* __restrict__ rtasks_next, int* __restrict__ rcnt_next,
                         Task* __restrict__ mtasks, int* __restrict__ mcnt,
                         const float* __restrict__ newh_buf,
                         const float* __restrict__ Wq1, const float* __restrict__ bq1,
                         const float* __restrict__ Wq2, const float* __restrict__ bq2,
                         float* __restrict__ out, int final_flag, int gen_refresh)
{
    int b = blockIdx.x, tid = threadIdx.x;
    __shared__ float nh[HD];
    __shared__ double part[64];
    __shared__ int sbest;
    int len = length[b];
    if (!final_flag) {
        for (int t = 0; t < 2; ++t) {
            int ti = rti_cur[b * 2 + t];
            if (ti < 0) continue;
            for (int c = tid; c < HD; c += 64) nh[c] = newh_buf[(long)ti * HD + c];
            __syncthreads();
            double p = 0.0;
            if (tid < HQ) {
                double a = (double)bq1[tid];
                const float* wr = &Wq1[(long)tid * HD];
                for (int k = 0; k < HD; ++k) a += (double)wr[k] * (double)nh[k];
                p = tanh(a) * (double)Wq2[tid];
            }
            part[tid] = p;
            __syncthreads();
            if (tid == 0) {
                double s = 0.0;
                for (int r = 0; r < HQ; ++r) s += part[r];
                s += (double)bq2[0];
                comp[b * TLEN + rtasks_cur[ti].jl] = (float)s;
            }
            __syncthreads();
        }
        int L1 = 63 - iter;
        if (tid == 0) {
            float best = -INFINITY; int bj = 0;
            for (int j = 0; j < L1; ++j) {
                float v = (iter + 1 + j < len) ? comp[b * TLEN + j] : -3.402823466e38f;
                if (v > best) { best = v; bj = j; }
            }
            sbest = bj;
        }
        __syncthreads();
        int bj = sbest;
        for (int j = tid; j < L1; j += 64) out[off_i + (long)b * L1 + j] = (j == bj) ? 1.0f : 0.0f;
        bool active = (iter + 1) < len;
        if (active) {
            if (tid == 0) {
                int mi = atomicAdd(mcnt, 1);
                Task t; t.b = b; t.sl = pos[b * TLEN + bj]; t.sr = pos[b * TLEN + bj + 1]; t.jl = bj;
                mtasks[mi] = t;
            }
            int newL = 63 - iter;
            int pv = 0;  bool dp = (tid >= bj + 1 && tid <= newL - 1);
            if (dp) pv = pos[b * TLEN + tid + 1];
            float cv = 0; bool dc = (tid >= bj + 1 && tid <= newL - 2);
            if (dc) cv = comp[b * TLEN + tid + 1];
            __syncthreads();
            if (dp) pos[b * TLEN + tid] = pv;
            if (dc) comp[b * TLEN + tid] = cv;
            __syncthreads();
            if (tid == 0) {
                if (gen_refresh) {
                    int vcnt = len - iter - 2;
                    for (int t = 0; t < 2; ++t) {
                        int jn = bj - 1 + t;
                        int r = -1;
                        if (jn >= 0 && jn < vcnt) {
                            r = atomicAdd(rcnt_next, 1);
                            Task tk; tk.b = b; tk.sl = pos[b * TLEN + jn]; tk.sr = pos[b * TLEN + jn + 1]; tk.jl = jn;
                            rtasks_next[r] = tk;
                        }
                        rti_next[b * 2 + t] = r;
                    }
                } else { rti_next[b * 2] = -1; rti_next[b * 2 + 1] = -1; }
            }
        } else {
            if (tid == 0) { rti_next[b * 2] = -1; rti_next[b * 2 + 1] = -1; }
        }
    } else {
        if (tid == 0 && len == TLEN) {
            int mi = atomicAdd(mcnt, 1);
            Task t; t.b = b; t.sl = pos[b * TLEN + 0]; t.sr = pos[b * TLEN + 1]; t.jl = 0;
            mtasks[mi] = t;
        }
    }
}

// ---------------- final output copy ----------------
__global__ void k_out(const float* __restrict__ h, float* __restrict__ out)
{
    int i = blockIdx.x * blockDim.x + threadIdx.x;
    if (i < BATCH * HD) {
        int b = i / HD, c = i % HD;
        out[i] = h[((long)b * TLEN + 0) * HD + c];
    }
}

extern "C" void kernel_launch(void* const* d_in, const int* in_sizes, int n_in,
                              void* d_out, int out_size, void* d_ws, size_t ws_size,
                              hipStream_t stream)
{
    const float* inp = (const float*)d_in[0];
    const int* length = (const int*)d_in[1];
    const float* W1 = (const float*)d_in[2];
    const float* b1 = (const float*)d_in[3];
    const float* W2 = (const float*)d_in[4];
    const float* b2 = (const float*)d_in[5];
    const float* Wq1 = (const float*)d_in[6];
    const float* bq1 = (const float*)d_in[7];
    const float* Wq2 = (const float*)d_in[8];
    const float* bq2 = (const float*)d_in[9];
    float* out = (float*)d_out;

    char* p = (char*)d_ws;
    auto alloc = [&](size_t bytes) { char* r = p; p += (bytes + 255) & ~(size_t)255; return r; };
    float* h      = (float*)alloc((size_t)BATCH * TLEN * HD * 4);
    float* W1T    = (float*)alloc((size_t)H2 * H3 * 4);
    float* W2T    = (float*)alloc((size_t)H2 * HD * 4);
    float* Vif    = (float*)alloc((size_t)CHUNK * H2 * 4);
    float* X2     = (float*)alloc((size_t)CHUNK * H2 * 4);
    float* newh   = (float*)alloc((size_t)CHUNK * HD * 4);
    float* comp   = (float*)alloc((size_t)BATCH * TLEN * 4);
    int*   pos    = (int*)alloc((size_t)BATCH * TLEN * 4);
    Task*  itasks = (Task*)alloc((size_t)BATCH * (TLEN - 1) * sizeof(Task));
    Task*  rtasks0 = (Task*)alloc((size_t)2 * BATCH * sizeof(Task));
    Task*  rtasks1 = (Task*)alloc((size_t)2 * BATCH * sizeof(Task));
    Task*  mtasks  = (Task*)alloc((size_t)BATCH * sizeof(Task));
    int*   rti0 = (int*)alloc(BATCH * 2 * 4);
    int*   rti1 = (int*)alloc(BATCH * 2 * 4);
    int*   counters = (int*)alloc(256);
    int* cnt_init = counters + 0;
    int* rcnt0 = counters + 1;
    int* rcnt1 = counters + 2;
    int* mcnt  = counters + 3;

    k_prep<<<2048, 256, 0, stream>>>(inp, W1, W2, h, W1T, W2T, pos, rti0, rti1, counters);
    k_init_tasks<<<BATCH, 64, 0, stream>>>(length, itasks, cnt_init);
    for (int c = 0; c < 8; ++c) {
        k_g1<<<dim3(CHUNK / 64, 24), 256, 0, stream>>>(itasks, cnt_init, c * CHUNK, h, W1T, b1, Vif, X2, nullptr, nullptr);
        k_g2<<<dim3(CHUNK / 64, 8), 256, 0, stream>>>(itasks, cnt_init, c * CHUNK, h, X2, Vif, W2T, b2, newh, 0);
        k_g3<<<CHUNK, 64, 0, stream>>>(itasks, cnt_init, c * CHUNK, newh, Wq1, bq1, Wq2, bq2, comp);
    }
    long offi = (long)BATCH * HD;
    for (int i = 0; i < 63; ++i) {
        int par = i & 1;
        Task* rt_cur = par ? rtasks1 : rtasks0;
        Task* rt_nxt = par ? rtasks0 : rtasks1;
        int* rc_cur = par ? rcnt1 : rcnt0;
        int* rc_nxt = par ? rcnt0 : rcnt1;
        int* ri_cur = par ? rti1 : rti0;
        int* ri_nxt = par ? rti0 : rti1;
        if (i >= 1) {
            k_g1<<<dim3(16, 24), 256, 0, stream>>>(rt_cur, rc_cur, 0, h, W1T, b1, Vif, X2, rc_nxt, mcnt);
            k_g2<<<dim3(16, 8), 256, 0, stream>>>(rt_cur, rc_cur, 0, h, X2, Vif, W2T, b2, newh, 0);
        }
        k_select<<<BATCH, 64, 0, stream>>>(i, offi, length, comp, pos, ri_cur, ri_nxt,
                                           rt_cur, rt_nxt, rc_nxt, mtasks, mcnt, newh,
                                           Wq1, bq1, Wq2, bq2, out, (i == 62) ? 1 : 0, (i < 61) ? 1 : 0);
        k_g1<<<dim3(8, 24), 256, 0, stream>>>(mtasks, mcnt, 0, h, W1T, b1, Vif, X2, nullptr, nullptr);
        k_g2<<<dim3(8, 8), 256, 0, stream>>>(mtasks, mcnt, 0, h, X2, Vif, W2T, b2, newh, 1);
        if (i < 62) offi += (long)BATCH * (63 - i);
    }
    k_out<<<(BATCH * HD + 255) / 256, 256, 0, stream>>>(h, out);
}

// Round 2
// 13687.669 us; speedup vs baseline: 1.5789x; 1.5789x over previous
//
#include <hip/hip_runtime.h>
#include <math.h>

#define BATCH 512
#define TLEN  64
#define HD    512
#define H2    1024
#define H3    1536
#define HQ    51
#define CHUNK 4096
#define ARENA_BIT 64

// node encoding: (slot | ARENA_BIT) -> arena row, else leaf (input) row
struct Task { int b, el, er, jl, slot; };

__device__ __forceinline__ float sigf(float x) { return 1.0f / (1.0f + expf(-x)); }

__device__ __forceinline__ const float* node_ptr(const float* __restrict__ inp,
                                                 const float* __restrict__ arena,
                                                 int b, int enc)
{
    const float* base = (enc & ARENA_BIT) ? arena : inp;
    return base + ((long)b * TLEN + (enc & (ARENA_BIT - 1))) * HD;
}

// ---------------- prep: weight transposes, posval/cidx/rti/counter init ----------------
__global__ void k_prep(const float* __restrict__ W1, const float* __restrict__ W2,
                       float* __restrict__ W1T, float* __restrict__ W2T,
                       int* __restrict__ posval, int* __restrict__ cidx,
                       int* __restrict__ rti0, int* __restrict__ rti1,
                       int* __restrict__ counters)
{
    long tid = (long)blockIdx.x * blockDim.x + threadIdx.x;
    long nth = (long)gridDim.x * blockDim.x;
    for (long i = tid; i < (long)H2 * H3; i += nth) {
        long k = i / H3, r = i - k * H3;
        W1T[i] = W1[r * H2 + k];
    }
    for (long i = tid; i < (long)H2 * HD; i += nth) {
        long k = i / HD, r = i - k * HD;
        W2T[i] = W2[r * H2 + k];
    }
    for (long i = tid; i < BATCH * TLEN; i += nth) {
        int j = (int)(i % TLEN);
        posval[i] = j;      // leaf
        cidx[i] = j;        // pair j cached in arena slot j
    }
    for (long i = tid; i < BATCH * 2; i += nth) { rti0[i] = -1; rti1[i] = -1; }
    if (tid < 8) counters[tid] = 0;
}

// ---------------- initial task list: all valid pairs (j < len-1) ----------------
__global__ void k_init_tasks(const int* __restrict__ length, Task* __restrict__ tasks, int* __restrict__ cnt)
{
    int b = blockIdx.x, j = threadIdx.x;
    int len = length[b];
    if (j < len - 1) {
        int idx = atomicAdd(cnt, 1);
        Task t; t.b = b; t.el = j; t.er = j + 1; t.jl = j; t.slot = j;
        tasks[idx] = t;
    }
}

// ---------------- G1: V = [hl,hr] @ W1^T + b1 ; r-part fused into X2 = [hl*rs, hr*rs] ----------------
// tile: 64 tasks x 64 cols of 1536, K=1024, BK=32, 256 threads, 4x4 micro
__launch_bounds__(256, 2)
__global__ void k_g1(const Task* __restrict__ tasks, const int* __restrict__ cnt, int task_off,
                     const float* __restrict__ inp, const float* __restrict__ arena,
                     const float* __restrict__ W1T, const float* __restrict__ b1,
                     float* __restrict__ Vif, float* __restrict__ X2, int* zc)
{
    if (zc && blockIdx.x == 0 && blockIdx.y == 0 && threadIdx.x == 0) *zc = 0;
    __shared__ float XsT[32][68];     // [k][row] transposed A tile
    __shared__ float Ws[32][64];
    __shared__ const float* pL[64];
    __shared__ const float* pR[64];
    __shared__ int tok[64];
    int count = *cnt;
    int m_base = task_off + blockIdx.x * 64;
    if (m_base >= count) return;
    int tid = threadIdx.x;
    if (tid < 64) {
        int mg = m_base + tid;
        if (mg < count) {
            Task t = tasks[mg];
            pL[tid] = node_ptr(inp, arena, t.b, t.el);
            pR[tid] = node_ptr(inp, arena, t.b, t.er);
            tok[tid] = 1;
        } else { pL[tid] = inp; pR[tid] = inp; tok[tid] = 0; }
    }
    __syncthreads();
    const int n0 = blockIdx.y * 64;
    const int ty = tid >> 4, tx = tid & 15;
    const int mrow = tid >> 2, mk = (tid & 3) * 8;
    const int wrow = tid >> 3, wn = (tid & 7) * 8;
    float acc[4][4] = {};
    for (int kt = 0; kt < 32; ++kt) {
        int k0 = kt * 32;
        {
            const float* src = (k0 < HD ? pL[mrow] : pR[mrow]) + (k0 < HD ? (k0 + mk) : (k0 + mk - HD));
            float4 v0 = *(const float4*)src;
            float4 v1 = *(const float4*)(src + 4);
            XsT[mk + 0][mrow] = v0.x; XsT[mk + 1][mrow] = v0.y;
            XsT[mk + 2][mrow] = v0.z; XsT[mk + 3][mrow] = v0.w;
            XsT[mk + 4][mrow] = v1.x; XsT[mk + 5][mrow] = v1.y;
            XsT[mk + 6][mrow] = v1.z; XsT[mk + 7][mrow] = v1.w;
        }
        {
            const float* src = &W1T[(long)(k0 + wrow) * H3 + n0 + wn];
            float4 v0 = *(const float4*)src;
            float4 v1 = *(const float4*)(src + 4);
            float* wd = &Ws[wrow][wn];
            *(float4*)wd = v0;
            *(float4*)(wd + 4) = v1;
        }
        __syncthreads();
        #pragma unroll
        for (int kk = 0; kk < 32; ++kk) {
            float4 av = *(const float4*)&XsT[kk][ty * 4];
            float4 wv = *(const float4*)&Ws[kk][tx * 4];
            acc[0][0] += av.x * wv.x; acc[0][1] += av.x * wv.y; acc[0][2] += av.x * wv.z; acc[0][3] += av.x * wv.w;
            acc[1][0] += av.y * wv.x; acc[1][1] += av.y * wv.y; acc[1][2] += av.y * wv.z; acc[1][3] += av.y * wv.w;
            acc[2][0] += av.z * wv.x; acc[2][1] += av.z * wv.y; acc[2][2] += av.z * wv.z; acc[2][3] += av.z * wv.w;
            acc[3][0] += av.w * wv.x; acc[3][1] += av.w * wv.y; acc[3][2] += av.w * wv.z; acc[3][3] += av.w * wv.w;
        }
        __syncthreads();
    }
    const int row0 = blockIdx.x * 64;
    #pragma unroll
    for (int mi = 0; mi < 4; ++mi) {
        int ml = ty * 4 + mi;
        if (!tok[ml]) continue;
        int row = row0 + ml;
        int c = n0 + tx * 4;
        float4 v;
        v.x = acc[mi][0] + b1[c + 0];
        v.y = acc[mi][1] + b1[c + 1];
        v.z = acc[mi][2] + b1[c + 2];
        v.w = acc[mi][3] + b1[c + 3];
        if (n0 < H2) {
            *(float4*)&Vif[(long)row * H2 + c] = v;
        } else {
            int c2 = c - H2;
            float4 rs;
            rs.x = sigf(v.x); rs.y = sigf(v.y); rs.z = sigf(v.z); rs.w = sigf(v.w);
            float4 l = *(const float4*)(pL[ml] + c2);
            float4 r = *(const float4*)(pR[ml] + c2);
            float4 xl, xr;
            xl.x = l.x * rs.x; xl.y = l.y * rs.y; xl.z = l.z * rs.z; xl.w = l.w * rs.w;
            xr.x = r.x * rs.x; xr.y = r.y * rs.y; xr.z = r.z * rs.z; xr.w = r.w * rs.w;
            *(float4*)&X2[(long)row * H2 + c2] = xl;
            *(float4*)&X2[(long)row * H2 + HD + c2] = xr;
        }
    }
}

// ---------------- G2: h_hat = X2 @ W2^T + b2 ; fused new_h epilogue -> arena[b][slot] ----------------
__launch_bounds__(256, 2)
__global__ void k_g2(const Task* __restrict__ tasks, const int* __restrict__ cnt, int task_off,
                     const float* __restrict__ inp, float* __restrict__ arena,
                     const float* __restrict__ X2, const float* __restrict__ Vif,
                     const float* __restrict__ W2T, const float* __restrict__ b2)
{
    __shared__ float XsT[32][68];
    __shared__ float Ws[32][64];
    __shared__ const float* pL[64];
    __shared__ const float* pR[64];
    __shared__ int dr[64];
    __shared__ int tok[64];
    int count = *cnt;
    int m_base = task_off + blockIdx.x * 64;
    if (m_base >= count) return;
    int tid = threadIdx.x;
    if (tid < 64) {
        int mg = m_base + tid;
        if (mg < count) {
            Task t = tasks[mg];
            pL[tid] = node_ptr(inp, arena, t.b, t.el);
            pR[tid] = node_ptr(inp, arena, t.b, t.er);
            dr[tid] = t.b * TLEN + t.slot;
            tok[tid] = 1;
        } else { pL[tid] = inp; pR[tid] = inp; dr[tid] = 0; tok[tid] = 0; }
    }
    __syncthreads();
    const int n0 = blockIdx.y * 64;
    const int ty = tid >> 4, tx = tid & 15;
    const int mrow = tid >> 2, mk = (tid & 3) * 8;
    const int wrow = tid >> 3, wn = (tid & 7) * 8;
    const int row0 = blockIdx.x * 64;
    float acc[4][4] = {};
    for (int kt = 0; kt < 32; ++kt) {
        int k0 = kt * 32;
        {
            const float* src = &X2[(long)(row0 + mrow) * H2 + k0 + mk];
            float4 v0 = *(const float4*)src;
            float4 v1 = *(const float4*)(src + 4);
            XsT[mk + 0][mrow] = v0.x; XsT[mk + 1][mrow] = v0.y;
            XsT[mk + 2][mrow] = v0.z; XsT[mk + 3][mrow] = v0.w;
            XsT[mk + 4][mrow] = v1.x; XsT[mk + 5][mrow] = v1.y;
            XsT[mk + 6][mrow] = v1.z; XsT[mk + 7][mrow] = v1.w;
        }
        {
            const float* src = &W2T[(long)(k0 + wrow) * HD + n0 + wn];
            float4 v0 = *(const float4*)src;
            float4 v1 = *(const float4*)(src + 4);
            float* wd = &Ws[wrow][wn];
            *(float4*)wd = v0;
            *(float4*)(wd + 4) = v1;
        }
        __syncthreads();
        #pragma unroll
        for (int kk = 0; kk < 32; ++kk) {
            float4 av = *(const float4*)&XsT[kk][ty * 4];
            float4 wv = *(const float4*)&Ws[kk][tx * 4];
            acc[0][0] += av.x * wv.x; acc[0][1] += av.x * wv.y; acc[0][2] += av.x * wv.z; acc[0][3] += av.x * wv.w;
            acc[1][0] += av.y * wv.x; acc[1][1] += av.y * wv.y; acc[1][2] += av.y * wv.z; acc[1][3] += av.y * wv.w;
            acc[2][0] += av.z * wv.x; acc[2][1] += av.z * wv.y; acc[2][2] += av.z * wv.z; acc[2][3] += av.z * wv.w;
            acc[3][0] += av.w * wv.x; acc[3][1] += av.w * wv.y; acc[3][2] += av.w * wv.z; acc[3][3] += av.w * wv.w;
        }
        __syncthreads();
    }
    #pragma unroll
    for (int mi = 0; mi < 4; ++mi) {
        int ml = ty * 4 + mi;
        if (!tok[ml]) continue;
        int row = row0 + ml;
        int c = n0 + tx * 4;
        float4 hh;
        hh.x = acc[mi][0] + b2[c + 0];
        hh.y = acc[mi][1] + b2[c + 1];
        hh.z = acc[mi][2] + b2[c + 2];
        hh.w = acc[mi][3] + b2[c + 3];
        float4 vi = *(const float4*)&Vif[(long)row * H2 + c];
        float4 vf = *(const float4*)&Vif[(long)row * H2 + HD + c];
        float4 l = *(const float4*)(pL[ml] + c);
        float4 r = *(const float4*)(pR[ml] + c);
        float4 nh;
        nh.x = (l.x + r.x) * sigf(vf.x) + tanhf(hh.x) * sigf(vi.x);
        nh.y = (l.y + r.y) * sigf(vf.y) + tanhf(hh.y) * sigf(vi.y);
        nh.z = (l.z + r.z) * sigf(vf.z) + tanhf(hh.z) * sigf(vi.z);
        nh.w = (l.w + r.w) * sigf(vf.w) + tanhf(hh.w) * sigf(vi.w);
        *(float4*)&arena[(long)dr[ml] * HD + c] = nh;
    }
}

// ---------------- G3 (init only): comp score per task from arena ----------------
__launch_bounds__(64)
__global__ void k_g3(const Task* __restrict__ tasks, const int* __restrict__ cnt, int task_off,
                     const float* __restrict__ arena,
                     const float* __restrict__ Wq1, const float* __restrict__ bq1,
                     const float* __restrict__ Wq2, const float* __restrict__ bq2,
                     float* __restrict__ comp)
{
    int tgl = task_off + blockIdx.x;
    if (tgl >= *cnt) return;
    Task t = tasks[tgl];
    int tid = threadIdx.x;
    __shared__ float nh[HD];
    __shared__ double part[64];
    const float* src = &arena[((long)t.b * TLEN + t.slot) * HD];
    for (int c = tid; c < HD; c += 64) nh[c] = src[c];
    __syncthreads();
    double p = 0.0;
    if (tid < HQ) {
        const float* wr = &Wq1[(long)tid * HD];
        double s0 = 0.0, s1 = 0.0, s2 = 0.0, s3 = 0.0;
        for (int k = 0; k < HD; k += 4) {
            s0 += (double)wr[k + 0] * (double)nh[k + 0];
            s1 += (double)wr[k + 1] * (double)nh[k + 1];
            s2 += (double)wr[k + 2] * (double)nh[k + 2];
            s3 += (double)wr[k + 3] * (double)nh[k + 3];
        }
        double a = (double)bq1[tid] + s0 + s1 + s2 + s3;
        p = tanh(a) * (double)Wq2[tid];
    }
    part[tid] = p;
    __syncthreads();
    if (tid == 0) {
        double s = 0.0;
        for (int r = 0; r < HQ; ++r) s += part[r];
        s += (double)bq2[0];
        comp[t.b * TLEN + t.jl] = (float)s;
    }
}

// ---------------- select: refresh comp (<=2), argmax, write mask, O(1) merge, emit refresh tasks ----------------
__launch_bounds__(64)
__global__ void k_select(int iter, long off_i, const int* __restrict__ length,
                         float* __restrict__ comp, int* __restrict__ posval, int* __restrict__ cidx,
                         const int* __restrict__ rti_cur, int* __restrict__ rti_next,
                         const Task* __restrict__ rtasks_cur, Task* __restrict__ rtasks_next, int* __restrict__ rcnt_next,
                         const float* __restrict__ arena,
                         const float* __restrict__ Wq1, const float* __restrict__ bq1,
                         const float* __restrict__ Wq2, const float* __restrict__ bq2,
                         float* __restrict__ out, int final_flag)
{
    int b = blockIdx.x, tid = threadIdx.x;
    __shared__ float nh[HD];
    __shared__ double part[64];
    __shared__ int sh[4];   // 0: best j, 1: sM, 2: sOld
    int len = length[b];
    if (final_flag) {
        // last iteration: for len==64 batches merge the final pair into the root
        if (tid == 0 && len == TLEN) posval[b * TLEN + 0] = ARENA_BIT | cidx[b * TLEN + 0];
        return;
    }
    // 1) refresh comp for pairs whose new_h was just recomputed
    for (int t = 0; t < 2; ++t) {
        int ti = rti_cur[b * 2 + t];
        if (ti < 0) continue;   // uniform per block
        Task tk = rtasks_cur[ti];
        const float* src = &arena[((long)b * TLEN + tk.slot) * HD];
        for (int c = tid; c < HD; c += 64) nh[c] = src[c];
        __syncthreads();
        double p = 0.0;
        if (tid < HQ) {
            const float* wr = &Wq1[(long)tid * HD];
            double s0 = 0.0, s1 = 0.0, s2 = 0.0, s3 = 0.0;
            for (int k = 0; k < HD; k += 4) {
                s0 += (double)wr[k + 0] * (double)nh[k + 0];
                s1 += (double)wr[k + 1] * (double)nh[k + 1];
                s2 += (double)wr[k + 2] * (double)nh[k + 2];
                s3 += (double)wr[k + 3] * (double)nh[k + 3];
            }
            double a = (double)bq1[tid] + s0 + s1 + s2 + s3;
            p = tanh(a) * (double)Wq2[tid];
        }
        part[tid] = p;
        __syncthreads();
        if (tid == 0) {
            double s = 0.0;
            for (int r = 0; r < HQ; ++r) s += part[r];
            s += (double)bq2[0];
            comp[b * TLEN + tk.jl] = (float)s;
        }
        __syncthreads();
    }
    // 2) argmax + mask
    int L1 = 63 - iter;
    if (tid == 0) {
        float best = -INFINITY; int bj = 0;
        for (int j = 0; j < L1; ++j) {
            float v = (iter + 1 + j < len) ? comp[b * TLEN + j] : -3.402823466e38f;
            if (v > best) { best = v; bj = j; }
        }
        sh[0] = bj;
    }
    __syncthreads();
    int bj = sh[0];
    for (int j = tid; j < L1; j += 64) out[off_i + (long)b * L1 + j] = (j == bj) ? 1.0f : 0.0f;
    bool active = (iter + 1) < len;
    if (active) {
        int vcnt = len - iter - 2;     // pair count after this merge
        if (tid == 0) {
            sh[1] = cidx[b * TLEN + bj];                                // slot of merged pair -> becomes node storage
            sh[2] = (bj < vcnt) ? cidx[b * TLEN + bj + 1] : -1;         // dead pair's slot -> reuse for new right pair
        }
        __syncthreads();
        int sM = sh[1], sOld = sh[2];
        int newL = 63 - iter;
        int pv = 0;  bool dp = (tid >= bj + 1 && tid <= newL - 1);
        if (dp) pv = posval[b * TLEN + tid + 1];
        float cv = 0; int civ = 0; bool dc = (tid >= bj + 1 && tid <= newL - 2);
        if (dc) { cv = comp[b * TLEN + tid + 1]; civ = cidx[b * TLEN + tid + 1]; }
        __syncthreads();
        if (dp) posval[b * TLEN + tid] = pv;
        if (dc) { comp[b * TLEN + tid] = cv; cidx[b * TLEN + tid] = civ; }
        if (tid == 0) posval[b * TLEN + bj] = ARENA_BIT | sM;   // merged node (O(1) "merge")
        __syncthreads();
        if (tid == 0) {
            for (int t = 0; t < 2; ++t) {
                int jn = bj - 1 + t;
                int r = -1;
                if (jn >= 0 && jn < vcnt) {
                    int slot = (t == 0) ? cidx[b * TLEN + jn] : sOld;
                    cidx[b * TLEN + jn] = slot;
                    r = atomicAdd(rcnt_next, 1);
                    Task tk; tk.b = b;
                    tk.el = posval[b * TLEN + jn];
                    tk.er = posval[b * TLEN + jn + 1];
                    tk.jl = jn; tk.slot = slot;
                    rtasks_next[r] = tk;
                }
                rti_next[b * 2 + t] = r;
            }
        }
    } else {
        if (tid == 0) { rti_next[b * 2] = -1; rti_next[b * 2 + 1] = -1; }
    }
}

// ---------------- final output copy: root node ----------------
__global__ void k_out(const int* __restrict__ posval, const float* __restrict__ inp,
                      const float* __restrict__ arena, float* __restrict__ out)
{
    int i = blockIdx.x * blockDim.x + threadIdx.x;
    if (i < BATCH * HD) {
        int b = i / HD, c = i % HD;
        const float* src = node_ptr(inp, arena, b, posval[b * TLEN + 0]);
        out[i] = src[c];
    }
}

extern "C" void kernel_launch(void* const* d_in, const int* in_sizes, int n_in,
                              void* d_out, int out_size, void* d_ws, size_t ws_size,
                              hipStream_t stream)
{
    const float* inp = (const float*)d_in[0];
    const int* length = (const int*)d_in[1];
    const float* W1 = (const float*)d_in[2];
    const float* b1 = (const float*)d_in[3];
    const float* W2 = (const float*)d_in[4];
    const float* b2 = (const float*)d_in[5];
    const float* Wq1 = (const float*)d_in[6];
    const float* bq1 = (const float*)d_in[7];
    const float* Wq2 = (const float*)d_in[8];
    const float* bq2 = (const float*)d_in[9];
    float* out = (float*)d_out;

    char* p = (char*)d_ws;
    auto alloc = [&](size_t bytes) { char* r = p; p += (bytes + 255) & ~(size_t)255; return r; };
    float* W1T    = (float*)alloc((size_t)H2 * H3 * 4);
    float* W2T    = (float*)alloc((size_t)H2 * HD * 4);
    float* Vif    = (float*)alloc((size_t)CHUNK * H2 * 4);
    float* X2     = (float*)alloc((size_t)CHUNK * H2 * 4);
    float* arena  = (float*)alloc((size_t)BATCH * TLEN * HD * 4);
    float* comp   = (float*)alloc((size_t)BATCH * TLEN * 4);
    int*   posval = (int*)alloc((size_t)BATCH * TLEN * 4);
    int*   cidx   = (int*)alloc((size_t)BATCH * TLEN * 4);
    Task*  itasks  = (Task*)alloc((size_t)BATCH * (TLEN - 1) * sizeof(Task));
    Task*  rtasks0 = (Task*)alloc((size_t)2 * BATCH * sizeof(Task));
    Task*  rtasks1 = (Task*)alloc((size_t)2 * BATCH * sizeof(Task));
    int*   rti0 = (int*)alloc(BATCH * 2 * 4);
    int*   rti1 = (int*)alloc(BATCH * 2 * 4);
    int*   counters = (int*)alloc(256);
    int* cnt_init = counters + 0;
    int* rcnt0 = counters + 1;
    int* rcnt1 = counters + 2;

    k_prep<<<2048, 256, 0, stream>>>(W1, W2, W1T, W2T, posval, cidx, rti0, rti1, counters);
    k_init_tasks<<<BATCH, 64, 0, stream>>>(length, itasks, cnt_init);
    for (int c = 0; c < 8; ++c) {
        k_g1<<<dim3(CHUNK / 64, 24), 256, 0, stream>>>(itasks, cnt_init, c * CHUNK, inp, arena, W1T, b1, Vif, X2, nullptr);
        k_g2<<<dim3(CHUNK / 64, 8), 256, 0, stream>>>(itasks, cnt_init, c * CHUNK, inp, arena, X2, Vif, W2T, b2);
        k_g3<<<CHUNK, 64, 0, stream>>>(itasks, cnt_init, c * CHUNK, arena, Wq1, bq1, Wq2, bq2, comp);
    }
    long offi = (long)BATCH * HD;
    for (int i = 0; i < 63; ++i) {
        int par = i & 1, nxt = par ^ 1;
        Task* rt_cur = par ? rtasks1 : rtasks0;
        Task* rt_nxt = par ? rtasks0 : rtasks1;
        int* rc_cur = par ? rcnt1 : rcnt0;
        int* rc_nxt = par ? rcnt0 : rcnt1;
        int* ri_cur = par ? rti1 : rti0;
        int* ri_nxt = par ? rti0 : rti1;
        (void)nxt;
        if (i >= 1) {
            k_g1<<<dim3(16, 24), 256, 0, stream>>>(rt_cur, rc_cur, 0, inp, arena, W1T, b1, Vif, X2, rc_nxt);
            k_g2<<<dim3(16, 8), 256, 0, stream>>>(rt_cur, rc_cur, 0, inp, arena, X2, Vif, W2T, b2);
        }
        k_select<<<BATCH, 64, 0, stream>>>(i, offi, length, comp, posval, cidx,
                                           ri_cur, ri_nxt, rt_cur, rt_nxt, rc_nxt,
                                           arena, Wq1, bq1, Wq2, bq2, out, (i == 62) ? 1 : 0);
        if (i < 62) offi += (long)BATCH * (63 - i);
    }
    k_out<<<(BATCH * HD + 255) / 256, 256, 0, stream>>>(posval, inp, arena, out);
}